// Round 6
// baseline (345.807 us; speedup 1.0000x reference)
//
#include <hip/hip_runtime.h>
#include <hip/hip_cooperative_groups.h>
#include <math.h>

namespace cg = cooperative_groups;

#define N_NODES 10000
#define N_EDGES 320000
#define F_IN 512
#define HID 256
#define PAD_DEG 80        // max in-degree ~60 (Poisson(32) over 10k nodes)
#define NBLK 512          // cooperative grid: 2 blocks/CU guaranteed resident
#define NWAVE (NBLK * 4)  // 2048 waves
#define EDGES_PER_BLK 625 // 512*625 = 320000 exactly

typedef _Float16 half8 __attribute__((ext_vector_type(8)));
typedef _Float16 half4v __attribute__((ext_vector_type(4)));
typedef float floatx4 __attribute__((ext_vector_type(4)));

typedef const __attribute__((address_space(1))) void* gas_ptr;
typedef __attribute__((address_space(3))) void* las_ptr;

// async global->LDS DMA, 16B/lane; LDS dst wave-uniform (HW appends lane*16)
__device__ __forceinline__ void dma16(const void* g, void* l) {
    __builtin_amdgcn_global_load_lds((gas_ptr)g, (las_ptr)l, 16, 0, 0);
}

__device__ __forceinline__ void fma4(float4& acc, float s, const float4& v) {
    acc.x += s * v.x; acc.y += s * v.y; acc.z += s * v.z; acc.w += s * v.w;
}

__device__ __forceinline__ float4 h4_to_f4(half4v h) {
    float4 f; f.x = (float)h[0]; f.y = (float)h[1]; f.z = (float)h[2]; f.w = (float)h[3];
    return f;
}

// One cooperative kernel, 4 phases separated by grid.sync():
//  p0: zero count + W1 -> transposed fp16 hi/lo split
//  p1: CSR build (all blocks, 625 edges each) then GEMM h0 = A@W1+b1 (fp16 out)
//  p2: u0 = relu(agg(h0)) @ W2 + b2   (gather traffic halved by fp16 h0)
//  p3: agg(u0) + Lorentz->Poincare pointwise
__global__ __launch_bounds__(256, 2) void k_fused(
    const float* __restrict__ A, const int* __restrict__ ei,
    const float* __restrict__ W1, const float* __restrict__ b1,
    const float* __restrict__ W2, const float* __restrict__ b2,
    const float* __restrict__ scale, float* __restrict__ out,
    int* __restrict__ count, int* __restrict__ csr,
    _Float16* __restrict__ h0h, float* __restrict__ u0,
    _Float16* __restrict__ Bt_hi, _Float16* __restrict__ Bt_lo)
{
    __shared__ float    As[2][2048];    // 16 KB  [buf][64r x 32k] fp32, chunk-swizzled
    __shared__ _Float16 Bhs[2][2048];   // 8 KB
    __shared__ _Float16 Bls[2][2048];   // 8 KB
    __shared__ int2     nb[4][PAD_DEG]; // 2.5 KB {src, weight-bits} per wave

    const int tid = threadIdx.x;
    const int b = blockIdx.x;
    const int lane = tid & 63, w = tid >> 6;
    cg::grid_group grid = cg::this_grid();

    // ===================== phase 0 =====================
    {
        int i = b * 256 + tid;            // 512*256 = 131072 = F_IN*HID exactly
        if (i < 10240) count[i] = 0;
        int k = i >> 8, n = i & 255;
        float v = W1[i];
        _Float16 hi = (_Float16)v;
        Bt_hi[n * F_IN + k] = hi;
        Bt_lo[n * F_IN + k] = (_Float16)(v - (float)hi);
    }
    grid.sync();

    // ===================== phase 1a: CSR build =====================
    {
        const int e0 = b * EDGES_PER_BLK;
        for (int j = tid; j < EDGES_PER_BLK; j += 256) {
            int e = e0 + j;
            int src = ei[e];
            int dst = ei[N_EDGES + e];
            int pos = atomicAdd(&count[dst], 1);   // final value = in-degree
            csr[dst * PAD_DEG + pos] = src;
        }
    }

    // ===================== phase 1b: GEMM (tile b; blocks<116 also 512+b) ==========
    {
        const int quad = lane >> 4, l15 = lane & 15;
        const int wm = (w >> 1) * 32, wn = (w & 1) * 32;   // wave = 32x32 sub-tile
        const int wdma = __builtin_amdgcn_readfirstlane(w);
        char* lA  = (char*)&As[0][0];    // buffer stride 8192 B
        char* lBh = (char*)&Bhs[0][0];   // buffer stride 4096 B
        char* lBl = (char*)&Bls[0][0];
        const int dA0u = wdma * 1024;
        const int dA1u = 4096 + wdma * 1024;
        const int dBu  = wdma * 1024;
        // per-lane global source slots (carry the XOR chunk swizzle)
        const int sA0 = tid, sA1 = tid + 256;
        const int rA0 = sA0 >> 3, hA0 = (sA0 & 7) ^ (rA0 & 7);
        const int rA1 = sA1 >> 3, hA1 = (sA1 & 7) ^ (rA1 & 7);
        const int cB = tid >> 2, hB = (tid & 3) ^ (cB & 3);
        // fragment LDS byte offsets (swizzled; constant per lane)
        int aoff[2][2], boff[2];
        #pragma unroll
        for (int mi = 0; mi < 2; ++mi) {
            int r = wm + mi * 16 + l15;
            aoff[mi][0] = r * 128 + ((2 * quad)     ^ (r & 7)) * 16;
            aoff[mi][1] = r * 128 + ((2 * quad + 1) ^ (r & 7)) * 16;
        }
        #pragma unroll
        for (int ni = 0; ni < 2; ++ni) {
            int nn = wn + ni * 16 + l15;
            boff[ni] = nn * 64 + (quad ^ (nn & 3)) * 16;
        }

        const int ntile = (b < 116) ? 2 : 1;   // tiles 0..511 + 512..627 = 628
        for (int tt = 0; tt < ntile; ++tt) {
            const int t = b + tt * 512;
            const int row0 = (t >> 2) * 64, col0 = (t & 3) * 64;
            int gr0 = row0 + rA0; if (gr0 > N_NODES - 1) gr0 = N_NODES - 1;
            int gr1 = row0 + rA1; if (gr1 > N_NODES - 1) gr1 = N_NODES - 1;
            const float* gA0 = A + (size_t)gr0 * F_IN + hA0 * 4;
            const float* gA1 = A + (size_t)gr1 * F_IN + hA1 * 4;
            const _Float16* gBh = Bt_hi + (size_t)(col0 + cB) * F_IN + hB * 8;
            const _Float16* gBl = Bt_lo + (size_t)(col0 + cB) * F_IN + hB * 8;
            floatx4 acc[2][2] = {};

            dma16(gA0, lA + dA0u);
            dma16(gA1, lA + dA1u);
            dma16(gBh, lBh + dBu);
            dma16(gBl, lBl + dBu);
            __syncthreads();                    // tile k-slice 0 resident

            int buf = 0;
            for (int it = 0; it < 16; ++it) {
                if (it < 15) {                  // next k-slice DMA, in flight under compute
                    const int k1 = (it + 1) * 32;
                    const int nbuf = buf ^ 1;
                    dma16(gA0 + k1, lA  + nbuf * 8192 + dA0u);
                    dma16(gA1 + k1, lA  + nbuf * 8192 + dA1u);
                    dma16(gBh + k1, lBh + nbuf * 4096 + dBu);
                    dma16(gBl + k1, lBl + nbuf * 4096 + dBu);
                }
                const char* bA = lA  + buf * 8192;
                const char* bH = lBh + buf * 4096;
                const char* bL = lBl + buf * 4096;
                half8 ah[2], al[2], bhf[2], blf[2];
                #pragma unroll
                for (int mi = 0; mi < 2; ++mi) {
                    float4 f0 = *(const float4*)(bA + aoff[mi][0]);
                    float4 f1 = *(const float4*)(bA + aoff[mi][1]);
                    float av[8] = {f0.x, f0.y, f0.z, f0.w, f1.x, f1.y, f1.z, f1.w};
                    #pragma unroll
                    for (int j = 0; j < 8; ++j) {
                        _Float16 h = (_Float16)av[j];
                        ah[mi][j] = h;
                        al[mi][j] = (_Float16)(av[j] - (float)h);
                    }
                }
                #pragma unroll
                for (int ni = 0; ni < 2; ++ni) {
                    bhf[ni] = *(const half8*)(bH + boff[ni]);
                    blf[ni] = *(const half8*)(bL + boff[ni]);
                }
                #pragma unroll
                for (int ni = 0; ni < 2; ++ni)
                    #pragma unroll
                    for (int mi = 0; mi < 2; ++mi) {
                        acc[mi][ni] = __builtin_amdgcn_mfma_f32_16x16x32_f16(ah[mi], bhf[ni], acc[mi][ni], 0, 0, 0);
                        acc[mi][ni] = __builtin_amdgcn_mfma_f32_16x16x32_f16(ah[mi], blf[ni], acc[mi][ni], 0, 0, 0);
                        acc[mi][ni] = __builtin_amdgcn_mfma_f32_16x16x32_f16(al[mi], bhf[ni], acc[mi][ni], 0, 0, 0);
                    }
                __syncthreads();                // drains DMA + all reads of buf done
                buf ^= 1;
            }
            // epilogue -> fp16 h0 (C/D layout: col=lane&15, row=quad*4+reg)
            #pragma unroll
            for (int mi = 0; mi < 2; ++mi)
                #pragma unroll
                for (int ni = 0; ni < 2; ++ni) {
                    int colb = col0 + wn + ni * 16 + l15;
                    float bias = b1[colb];
                    #pragma unroll
                    for (int reg = 0; reg < 4; ++reg) {
                        int rowb = row0 + wm + mi * 16 + quad * 4 + reg;
                        if (rowb < N_NODES)
                            h0h[(size_t)rowb * HID + colb] = (_Float16)(acc[mi][ni][reg] + bias);
                    }
                }
        }
    }
    grid.sync();

    // ===================== phase 2: u0 = relu(agg(h0)) @ W2 + b2 =====================
    {
        const int gw = b * 4 + w;               // global wave id 0..2047
        const int off = lane << 2;              // half index: 4 halves (8B) per lane
        #pragma unroll 1
        for (int itn = 0; itn < 5; ++itn) {     // uniform trip: ceil(10000/2048) = 5
            const int n = gw + itn * NWAVE;
            const bool act = n < N_NODES;
            int deg = 0;
            if (act) {
                deg = count[n];
                const float degd = (float)(deg > 0 ? deg : 1);
                const int* row = csr + (size_t)n * PAD_DEG;
                for (int j = lane; j < deg; j += 64) {   // parallel metadata preload
                    int s = row[j];
                    int cs = count[s];
                    float wq = rsqrtf((float)(cs > 0 ? cs : 1) * degd);
                    nb[w][j] = make_int2(s, __float_as_int(wq));
                }
            }
            __syncthreads();                    // uniform barrier (all waves, all blocks)
            if (act) {
                float4 acc0 = {0,0,0,0}, acc1 = {0,0,0,0}, acc2 = {0,0,0,0}, acc3 = {0,0,0,0};
                int j = 0;
                for (; j + 16 <= deg; j += 16) {
                    int2 e[16];
                    #pragma unroll
                    for (int q = 0; q < 16; ++q) e[q] = nb[w][j + q];
                    half4v v[16];
                    #pragma unroll
                    for (int q = 0; q < 16; ++q)
                        v[q] = *(const half4v*)(h0h + ((size_t)e[q].x << 8) + off);
                    #pragma unroll
                    for (int q = 0; q < 16; q += 4) {
                        fma4(acc0, __int_as_float(e[q + 0].y), h4_to_f4(v[q + 0]));
                        fma4(acc1, __int_as_float(e[q + 1].y), h4_to_f4(v[q + 1]));
                        fma4(acc2, __int_as_float(e[q + 2].y), h4_to_f4(v[q + 2]));
                        fma4(acc3, __int_as_float(e[q + 3].y), h4_to_f4(v[q + 3]));
                    }
                }
                for (; j + 4 <= deg; j += 4) {
                    int2 e0 = nb[w][j+0], e1 = nb[w][j+1], e2 = nb[w][j+2], e3 = nb[w][j+3];
                    half4v v0 = *(const half4v*)(h0h + ((size_t)e0.x << 8) + off);
                    half4v v1 = *(const half4v*)(h0h + ((size_t)e1.x << 8) + off);
                    half4v v2 = *(const half4v*)(h0h + ((size_t)e2.x << 8) + off);
                    half4v v3 = *(const half4v*)(h0h + ((size_t)e3.x << 8) + off);
                    fma4(acc0, __int_as_float(e0.y), h4_to_f4(v0));
                    fma4(acc1, __int_as_float(e1.y), h4_to_f4(v1));
                    fma4(acc2, __int_as_float(e2.y), h4_to_f4(v2));
                    fma4(acc3, __int_as_float(e3.y), h4_to_f4(v3));
                }
                for (; j < deg; ++j) {
                    int2 e = nb[w][j];
                    half4v v = *(const half4v*)(h0h + ((size_t)e.x << 8) + off);
                    fma4(acc0, __int_as_float(e.y), h4_to_f4(v));
                }
                acc0.x += acc1.x + acc2.x + acc3.x;
                acc0.y += acc1.y + acc2.y + acc3.y;
                acc0.z += acc1.z + acc2.z + acc3.z;
                acc0.w += acc1.w + acc2.w + acc3.w;
                acc0.x = fmaxf(acc0.x, 0.f); acc0.y = fmaxf(acc0.y, 0.f);
                acc0.z = fmaxf(acc0.z, 0.f); acc0.w = fmaxf(acc0.w, 0.f);
                float4 wa = *(const float4*)(W2 + (lane << 3));
                float4 wb = *(const float4*)(W2 + (lane << 3) + 4);
                float p0 = acc0.x * wa.x + acc0.y * wa.z + acc0.z * wb.x + acc0.w * wb.z;
                float p1 = acc0.x * wa.y + acc0.y * wa.w + acc0.z * wb.y + acc0.w * wb.w;
                #pragma unroll
                for (int o = 32; o > 0; o >>= 1) {
                    p0 += __shfl_down(p0, o);
                    p1 += __shfl_down(p1, o);
                }
                if (lane == 0) {
                    u0[2 * n]     = p0 + b2[0];
                    u0[2 * n + 1] = p1 + b2[1];
                }
            }
        }
    }
    grid.sync();

    // ===================== phase 3: agg(u0) + Lorentz->Poincare =====================
    {
        for (int n = b * 4 + w; n < N_NODES; n += NWAVE) {
            int deg = count[n];
            float degd = (float)(deg > 0 ? deg : 1);
            const int* row = csr + (size_t)n * PAD_DEG;
            float a0 = 0.f, a1 = 0.f;
            for (int j = lane; j < deg; j += 64) {
                int s = row[j];
                int cs = count[s];
                float wq = rsqrtf((float)(cs > 0 ? cs : 1) * degd);
                float2 uv = *(const float2*)(u0 + 2 * (size_t)s);
                a0 += wq * uv.x;
                a1 += wq * uv.y;
            }
            #pragma unroll
            for (int o = 32; o > 0; o >>= 1) {
                a0 += __shfl_down(a0, o);
                a1 += __shfl_down(a1, o);
            }
            if (lane == 0) {
                float un = fmaxf(sqrtf(a0 * a0 + a1 * a1), 1e-15f);
                float t = tanhf(0.5f * un) / un;   // sinh/(1+cosh)==tanh(x/2)
                float p0 = a0 * t, p1 = a1 * t;
                float pn = fmaxf(sqrtf(p0 * p0 + p1 * p1), 1e-12f);
                float s = fminf(fmaxf(scale[0], 0.666f), 0.999f);
                p0 = p0 / pn * s; p1 = p1 / pn * s;
                float nn = fmaxf(sqrtf(p0 * p0 + p1 * p1), 1e-15f);
                if (nn > 1.0f) { p0 = p0 / nn; p1 = p1 / nn; }
                out[2 * n]     = p0;
                out[2 * n + 1] = p1;
            }
        }
    }
}

// ---------------- launch ----------------

extern "C" void kernel_launch(void* const* d_in, const int* in_sizes, int n_in,
                              void* d_out, int out_size, void* d_ws, size_t ws_size,
                              hipStream_t stream) {
    const float* feature = (const float*)d_in[0];
    const int*   ei      = (const int*)d_in[1];
    const float* W1      = (const float*)d_in[2];
    const float* b1      = (const float*)d_in[3];
    const float* W2      = (const float*)d_in[4];
    const float* b2      = (const float*)d_in[5];
    const float* scale   = (const float*)d_in[6];
    float* out = (float*)d_out;

    // workspace layout (byte offsets, 16B-aligned)
    char* Wb = (char*)d_ws;
    int*      count = (int*)Wb;                     // 10240 ints
    int*      csr   = (int*)(Wb + 40960);           // 800000 ints
    _Float16* h0h   = (_Float16*)(Wb + 3240960);    // 10000*256 fp16 (5.12 MB)
    float*    u0    = (float*)(Wb + 8360960);       // 20000 floats
    _Float16* Bt_hi = (_Float16*)(Wb + 8440960);    // 256*512 halves
    _Float16* Bt_lo = (_Float16*)(Wb + 8703104);    // 256*512 halves (~9 MB total)

    void* args[] = {(void*)&feature, (void*)&ei, (void*)&W1, (void*)&b1,
                    (void*)&W2, (void*)&b2, (void*)&scale, (void*)&out,
                    (void*)&count, (void*)&csr, (void*)&h0h, (void*)&u0,
                    (void*)&Bt_hi, (void*)&Bt_lo};
    hipLaunchCooperativeKernel((const void*)k_fused, dim3(NBLK), dim3(256),
                               args, 0, stream);
}

// Round 7
// 134.750 us; speedup vs baseline: 2.5663x; 2.5663x over previous
//
#include <hip/hip_runtime.h>
#include <math.h>

#define N_NODES 10000
#define N_EDGES 320000
#define F_IN 512
#define HID 256
#define PAD_DEG 80      // max in-degree ~60 (Poisson(32) over 10k nodes); 80 is +8.5 sigma
#define N_GEMM_BLKS 632 // 79 row-panels x 4 col-tiles = 628, padded to 632 = 8*79
#define BUILD_BLKS ((N_EDGES + 255) / 256)   // 1250

typedef _Float16 half8 __attribute__((ext_vector_type(8)));
typedef _Float16 half4v __attribute__((ext_vector_type(4)));
typedef float floatx4 __attribute__((ext_vector_type(4)));

typedef const __attribute__((address_space(1))) void* gas_ptr;
typedef __attribute__((address_space(3))) void* las_ptr;

// async global->LDS DMA, 16B/lane; LDS dst wave-uniform (HW appends lane*16)
__device__ __forceinline__ void dma16(const void* g, void* l) {
    __builtin_amdgcn_global_load_lds((gas_ptr)g, (las_ptr)l, 16, 0, 0);
}

__device__ __forceinline__ void fma4(float4& acc, float s, const float4& v) {
    acc.x += s * v.x; acc.y += s * v.y; acc.z += s * v.z; acc.w += s * v.w;
}

__device__ __forceinline__ float4 h4_to_f4(half4v h) {
    float4 f; f.x = (float)h[0]; f.y = (float)h[1]; f.z = (float)h[2]; f.w = (float)h[3];
    return f;
}

// ---- k_pre: zero degree counters + W1 [512][256] -> transposed fp16 hi/lo split ----

__global__ __launch_bounds__(256) void k_pre(const float* __restrict__ W1,
                                             int* __restrict__ count,
                                             _Float16* __restrict__ Bt_hi,
                                             _Float16* __restrict__ Bt_lo) {
    int i = blockIdx.x * blockDim.x + threadIdx.x;
    if (i < 10240) count[i] = 0;
    int k = i >> 8, n = i & 255;
    float v = W1[i];
    _Float16 hi = (_Float16)v;
    Bt_hi[n * F_IN + k] = hi;
    Bt_lo[n * F_IN + k] = (_Float16)(v - (float)hi);
}

// ---- k_main: DMA-fed GEMM (blocks 0..631) || CSR build (blocks 632..1881) ----
// Identical to round 5 (148.4 us verified) except the epilogue stores h0 as FP16:
// halves the h0 write traffic here and the 327 MB gather traffic in k_agg1.
// fp16-h0 numerics harness-proven in round 6 (absmax 3.9e-3, passed).

__global__ __launch_bounds__(256) void k_main(const float* __restrict__ A,
                                              const _Float16* __restrict__ Bt_hi,
                                              const _Float16* __restrict__ Bt_lo,
                                              const float* __restrict__ b1,
                                              _Float16* __restrict__ h0h,
                                              const int* __restrict__ ei,
                                              int* __restrict__ count,
                                              int* __restrict__ csr) {
    __shared__ float    As[2][2048];     // [buf][64 rows x 32 k] fp32, chunk-swizzled
    __shared__ _Float16 Bhs[2][2048];    // [buf][64 cols x 32 k] fp16 hi, chunk-swizzled
    __shared__ _Float16 Bls[2][2048];    // [buf][64 cols x 32 k] fp16 lo
    const int tid = threadIdx.x;

    if (blockIdx.x >= N_GEMM_BLKS) {
        // ---------- CSR build half ----------
        int e = (blockIdx.x - N_GEMM_BLKS) * 256 + tid;
        if (e < N_EDGES) {
            int src = ei[e];
            int dst = ei[N_EDGES + e];
            int pos = atomicAdd(&count[dst], 1);   // final value = in-degree
            csr[dst * PAD_DEG + pos] = src;
        }
        return;
    }

    // ---------- GEMM half: h0 = feature @ W1 + b1, 3-term fp16-split MFMA ----------
    const int b = blockIdx.x;
    const int t = (b & 7) * 79 + (b >> 3);          // XCD swizzle, bijective over 0..631
    const int row0 = (t >> 2) * 64, col0 = (t & 3) * 64;   // t>=628 -> pad block

    // --- per-lane GLOBAL source addresses (carry the XOR chunk swizzle) ---
    const int sA0 = tid, sA1 = tid + 256;
    const int rA0 = sA0 >> 3, hA0 = (sA0 & 7) ^ (rA0 & 7);
    const int rA1 = sA1 >> 3, hA1 = (sA1 & 7) ^ (rA1 & 7);
    int gr0 = row0 + rA0; if (gr0 > N_NODES - 1) gr0 = N_NODES - 1;   // clamp pad rows
    int gr1 = row0 + rA1; if (gr1 > N_NODES - 1) gr1 = N_NODES - 1;
    const float* gA0 = A + (size_t)gr0 * F_IN + hA0 * 4;
    const float* gA1 = A + (size_t)gr1 * F_IN + hA1 * 4;
    const int cB = tid >> 2, hB = (tid & 3) ^ (cB & 3);
    const _Float16* gBh = Bt_hi + (size_t)(col0 + cB) * F_IN + hB * 8;
    const _Float16* gBl = Bt_lo + (size_t)(col0 + cB) * F_IN + hB * 8;

    // --- WAVE-UNIFORM LDS destinations (SGPR via readfirstlane) ---
    const int wdma = __builtin_amdgcn_readfirstlane(tid >> 6);  // wave id 0..3
    char* lA  = (char*)&As[0][0];    // buffer stride 8192 B
    char* lBh = (char*)&Bhs[0][0];   // buffer stride 4096 B
    char* lBl = (char*)&Bls[0][0];
    const int dA0u = wdma * 1024;
    const int dA1u = 4096 + wdma * 1024;
    const int dBu  = wdma * 1024;

    // prologue: tile 0 -> buf 0
    dma16(gA0, lA + dA0u);
    dma16(gA1, lA + dA1u);
    dma16(gBh, lBh + dBu);
    dma16(gBl, lBl + dBu);

    const int lane = tid & 63, w = tid >> 6;
    const int quad = lane >> 4, l15 = lane & 15;
    const int wm = (w >> 1) * 32, wn = (w & 1) * 32;   // wave = 32x32 sub-tile
    floatx4 acc[2][2] = {};

    // fragment LDS byte offsets (swizzled; constant per lane)
    int aoff[2][2], boff[2];
    #pragma unroll
    for (int mi = 0; mi < 2; ++mi) {
        int r = wm + mi * 16 + l15;
        aoff[mi][0] = r * 128 + ((2 * quad)     ^ (r & 7)) * 16;
        aoff[mi][1] = r * 128 + ((2 * quad + 1) ^ (r & 7)) * 16;
    }
    #pragma unroll
    for (int ni = 0; ni < 2; ++ni) {
        int n = wn + ni * 16 + l15;
        boff[ni] = n * 64 + (quad ^ (n & 3)) * 16;
    }

    __syncthreads();                                   // tile 0 resident

    int buf = 0;
    for (int it = 0; it < 16; ++it) {
        if (it < 15) {                  // next k-slice DMA, in flight under compute
            const int k1 = (it + 1) * 32;
            const int nb = buf ^ 1;
            dma16(gA0 + k1, lA  + nb * 8192 + dA0u);
            dma16(gA1 + k1, lA  + nb * 8192 + dA1u);
            dma16(gBh + k1, lBh + nb * 4096 + dBu);
            dma16(gBl + k1, lBl + nb * 4096 + dBu);
        }
        const char* bA = lA  + buf * 8192;
        const char* bH = lBh + buf * 4096;
        const char* bL = lBl + buf * 4096;
        half8 ah[2], al[2], bhf[2], blf[2];
        #pragma unroll
        for (int mi = 0; mi < 2; ++mi) {
            float4 f0 = *(const float4*)(bA + aoff[mi][0]);
            float4 f1 = *(const float4*)(bA + aoff[mi][1]);
            float av[8] = {f0.x, f0.y, f0.z, f0.w, f1.x, f1.y, f1.z, f1.w};
            #pragma unroll
            for (int j = 0; j < 8; ++j) {
                _Float16 h = (_Float16)av[j];
                ah[mi][j] = h;
                al[mi][j] = (_Float16)(av[j] - (float)h);
            }
        }
        #pragma unroll
        for (int ni = 0; ni < 2; ++ni) {
            bhf[ni] = *(const half8*)(bH + boff[ni]);
            blf[ni] = *(const half8*)(bL + boff[ni]);
        }
        #pragma unroll
        for (int ni = 0; ni < 2; ++ni)
            #pragma unroll
            for (int mi = 0; mi < 2; ++mi) {
                acc[mi][ni] = __builtin_amdgcn_mfma_f32_16x16x32_f16(ah[mi], bhf[ni], acc[mi][ni], 0, 0, 0);
                acc[mi][ni] = __builtin_amdgcn_mfma_f32_16x16x32_f16(ah[mi], blf[ni], acc[mi][ni], 0, 0, 0);
                acc[mi][ni] = __builtin_amdgcn_mfma_f32_16x16x32_f16(al[mi], bhf[ni], acc[mi][ni], 0, 0, 0);
            }
        __syncthreads();   // drains DMA (next tile ready) + all reads of buf done
        buf ^= 1;
    }

    // epilogue -> fp16 h0 (C/D layout: col=lane&15, row=quad*4+reg)
    #pragma unroll
    for (int mi = 0; mi < 2; ++mi)
        #pragma unroll
        for (int ni = 0; ni < 2; ++ni) {
            int colb = col0 + wn + ni * 16 + l15;
            float bias = b1[colb];
            #pragma unroll
            for (int reg = 0; reg < 4; ++reg) {
                int rowb = row0 + wm + mi * 16 + quad * 4 + reg;
                if (rowb < N_NODES)
                    h0h[(size_t)rowb * HID + colb] = (_Float16)(acc[mi][ni][reg] + bias);
            }
        }
}

// ---- k_agg1: u0 = relu(agg(h0)) @ W2 + b2 ----
// one wave/node; neighbor metadata preloaded in parallel into LDS; inner loop
// 16 independent 512B gathers in flight. h0 now fp16: gather bytes HALVED.

__global__ __launch_bounds__(256) void k_agg1(const _Float16* __restrict__ h0h,
                                              const int* __restrict__ csr,
                                              const int* __restrict__ count,
                                              const float* __restrict__ W2,
                                              const float* __restrict__ b2,
                                              float* __restrict__ u0) {
    __shared__ int2 nb[4][PAD_DEG];                   // {src, weight-bits} per wave
    const int wid = threadIdx.x >> 6;
    const int lane = threadIdx.x & 63;
    const int n = blockIdx.x * 4 + wid;               // grid = 2500 -> n < 10000 always
    const int deg = count[n];
    const float degd = (float)(deg > 0 ? deg : 1);
    const int* row = csr + (size_t)n * PAD_DEG;
    for (int j = lane; j < deg; j += 64) {            // parallel preload (deg <= 80)
        int s = row[j];
        int cs = count[s];
        float wq = rsqrtf((float)(cs > 0 ? cs : 1) * degd);
        nb[wid][j] = make_int2(s, __float_as_int(wq));
    }
    __syncthreads();                                  // all waves reach (no early return)

    const int off = lane << 2;                        // 4 halves (8B) per lane
    float4 acc0 = {0,0,0,0}, acc1 = {0,0,0,0}, acc2 = {0,0,0,0}, acc3 = {0,0,0,0};
    int j = 0;
    for (; j + 16 <= deg; j += 16) {
        int2 e[16];
        #pragma unroll
        for (int q = 0; q < 16; ++q) e[q] = nb[wid][j + q];
        half4v v[16];
        #pragma unroll
        for (int q = 0; q < 16; ++q)
            v[q] = *(const half4v*)(h0h + ((size_t)e[q].x << 8) + off);
        #pragma unroll
        for (int q = 0; q < 16; q += 4) {
            fma4(acc0, __int_as_float(e[q + 0].y), h4_to_f4(v[q + 0]));
            fma4(acc1, __int_as_float(e[q + 1].y), h4_to_f4(v[q + 1]));
            fma4(acc2, __int_as_float(e[q + 2].y), h4_to_f4(v[q + 2]));
            fma4(acc3, __int_as_float(e[q + 3].y), h4_to_f4(v[q + 3]));
        }
    }
    for (; j + 4 <= deg; j += 4) {
        int2 e0 = nb[wid][j+0], e1 = nb[wid][j+1], e2 = nb[wid][j+2], e3 = nb[wid][j+3];
        half4v v0 = *(const half4v*)(h0h + ((size_t)e0.x << 8) + off);
        half4v v1 = *(const half4v*)(h0h + ((size_t)e1.x << 8) + off);
        half4v v2 = *(const half4v*)(h0h + ((size_t)e2.x << 8) + off);
        half4v v3 = *(const half4v*)(h0h + ((size_t)e3.x << 8) + off);
        fma4(acc0, __int_as_float(e0.y), h4_to_f4(v0));
        fma4(acc1, __int_as_float(e1.y), h4_to_f4(v1));
        fma4(acc2, __int_as_float(e2.y), h4_to_f4(v2));
        fma4(acc3, __int_as_float(e3.y), h4_to_f4(v3));
    }
    for (; j < deg; ++j) {
        int2 e = nb[wid][j];
        half4v v = *(const half4v*)(h0h + ((size_t)e.x << 8) + off);
        fma4(acc0, __int_as_float(e.y), h4_to_f4(v));
    }
    acc0.x += acc1.x + acc2.x + acc3.x;
    acc0.y += acc1.y + acc2.y + acc3.y;
    acc0.z += acc1.z + acc2.z + acc3.z;
    acc0.w += acc1.w + acc2.w + acc3.w;
    acc0.x = fmaxf(acc0.x, 0.f); acc0.y = fmaxf(acc0.y, 0.f);
    acc0.z = fmaxf(acc0.z, 0.f); acc0.w = fmaxf(acc0.w, 0.f);
    float4 wa = *(const float4*)(W2 + (lane << 3));
    float4 wb = *(const float4*)(W2 + (lane << 3) + 4);
    float p0 = acc0.x * wa.x + acc0.y * wa.z + acc0.z * wb.x + acc0.w * wb.z;
    float p1 = acc0.x * wa.y + acc0.y * wa.w + acc0.z * wb.y + acc0.w * wb.w;
    #pragma unroll
    for (int o = 32; o > 0; o >>= 1) {
        p0 += __shfl_down(p0, o);
        p1 += __shfl_down(p1, o);
    }
    if (lane == 0) {
        u0[2 * n]     = p0 + b2[0];
        u0[2 * n + 1] = p1 + b2[1];
    }
}

// ---- k_agg2: second aggregation + Lorentz->Poincare pointwise (weights inline) ----

__global__ __launch_bounds__(256) void k_agg2(const float* __restrict__ u0,
                                              const int* __restrict__ csr,
                                              const int* __restrict__ count,
                                              const float* __restrict__ scale,
                                              float* __restrict__ out) {
    int n = blockIdx.x * 4 + (threadIdx.x >> 6);
    int lane = threadIdx.x & 63;
    if (n >= N_NODES) return;
    int deg = count[n];
    float degd = (float)(deg > 0 ? deg : 1);
    const int* row = csr + (size_t)n * PAD_DEG;
    float a0 = 0.f, a1 = 0.f;
    for (int j = lane; j < deg; j += 64) {
        int s = row[j];
        int cs = count[s];
        float wq = rsqrtf((float)(cs > 0 ? cs : 1) * degd);
        float2 uv = *(const float2*)(u0 + 2 * (size_t)s);
        a0 += wq * uv.x;
        a1 += wq * uv.y;
    }
    #pragma unroll
    for (int o = 32; o > 0; o >>= 1) {
        a0 += __shfl_down(a0, o);
        a1 += __shfl_down(a1, o);
    }
    if (lane == 0) {
        float un = fmaxf(sqrtf(a0 * a0 + a1 * a1), 1e-15f);
        float t = tanhf(0.5f * un) / un;   // sinh/(1+cosh)==tanh(x/2), overflow-proof
        float p0 = a0 * t, p1 = a1 * t;
        float pn = fmaxf(sqrtf(p0 * p0 + p1 * p1), 1e-12f);
        float s = fminf(fmaxf(scale[0], 0.666f), 0.999f);
        p0 = p0 / pn * s; p1 = p1 / pn * s;
        float nn = fmaxf(sqrtf(p0 * p0 + p1 * p1), 1e-15f);
        if (nn > 1.0f) { p0 = p0 / nn; p1 = p1 / nn; }   // (1-1e-15)==1.0f in fp32
        out[2 * n]     = p0;
        out[2 * n + 1] = p1;
    }
}

// ---------------- launch ----------------

extern "C" void kernel_launch(void* const* d_in, const int* in_sizes, int n_in,
                              void* d_out, int out_size, void* d_ws, size_t ws_size,
                              hipStream_t stream) {
    const float* feature = (const float*)d_in[0];
    const int*   ei      = (const int*)d_in[1];
    const float* W1      = (const float*)d_in[2];
    const float* b1      = (const float*)d_in[3];
    const float* W2      = (const float*)d_in[4];
    const float* b2      = (const float*)d_in[5];
    const float* scale   = (const float*)d_in[6];
    float* out = (float*)d_out;

    // workspace layout (byte offsets, 16B-aligned)
    char* Wb = (char*)d_ws;
    int*      count = (int*)Wb;                     // 10240 ints
    int*      csr   = (int*)(Wb + 40960);           // 800000 ints
    _Float16* h0h   = (_Float16*)(Wb + 3240960);    // 10000*256 fp16 (5.12 MB)
    float*    u0    = (float*)(Wb + 8360960);       // 20000 floats
    _Float16* Bt_hi = (_Float16*)(Wb + 8440960);    // 256*512 halves
    _Float16* Bt_lo = (_Float16*)(Wb + 8703104);    // 256*512 halves (~9 MB total)

    k_pre<<<dim3(512), dim3(256), 0, stream>>>(W1, count, Bt_hi, Bt_lo);
    k_main<<<dim3(N_GEMM_BLKS + BUILD_BLKS), dim3(256), 0, stream>>>(
        feature, Bt_hi, Bt_lo, b1, h0h, ei, count, csr);
    k_agg1<<<dim3((N_NODES + 3) / 4), dim3(256), 0, stream>>>(h0h, csr, count, W2, b2, u0);
    k_agg2<<<dim3((N_NODES + 3) / 4), dim3(256), 0, stream>>>(u0, csr, count, scale, out);
}